// Round 6
// baseline (236.325 us; speedup 1.0000x reference)
//
#include <hip/hip_runtime.h>
#include <math.h>

#define BB 8
#define LL 2048
#define QQ 512
#define DD 512

// Strict-> insert: exact when scanned in increasing q (monotone index order).
__device__ __forceinline__ void top3_insert(float v, int i, float& m0,
                                            float& m1, float& m2, int& j0,
                                            int& j1, int& j2) {
  bool gt0 = v > m0, gt1 = v > m1, gt2 = v > m2;
  float nv2 = gt1 ? m1 : (gt2 ? v : m2);
  int   ni2 = gt1 ? j1 : (gt2 ? i : j2);
  float nv1 = gt0 ? m0 : (gt1 ? v : m1);
  int   ni1 = gt0 ? j0 : (gt1 ? i : j1);
  m0 = gt0 ? v : m0;
  j0 = gt0 ? i : j0;
  m1 = nv1; j1 = ni1; m2 = nv2; j2 = ni2;
}

// Tie-exact insert (value desc, index asc) — required for the non-monotone
// chunk merge to match JAX top_k's lowest-index-wins tie semantics.
__device__ __forceinline__ void top3_tie(float v, int i, float& m0, float& m1,
                                         float& m2, int& j0, int& j1,
                                         int& j2) {
  bool b0 = (v > m0) || ((v == m0) && (i < j0));
  bool b1 = (v > m1) || ((v == m1) && (i < j1));
  bool b2 = (v > m2) || ((v == m2) && (i < j2));
  float nv2 = b1 ? m1 : (b2 ? v : m2);
  int   nj2 = b1 ? j1 : (b2 ? i : j2);
  float nv1 = b0 ? m0 : (b1 ? v : m1);
  int   nj1 = b0 ? j0 : (b1 ? i : j1);
  m0 = b0 ? v : m0;
  j0 = b0 ? i : j0;
  m1 = nv1; j1 = nj1; m2 = nv2; j2 = nj2;
}

// Fully fused: top-3 scan + merge + softmax + emb gather + transpose store.
// Grid (64 l-tiles, 8 b), block 512 = 8 waves; block owns (b, 32 l's) and all
// 2048 logits rows. NO LDS aliasing; separate buffers, 54.8 KB -> 2 blocks/CU.
//   Phase 0: wave g -> (head g>>1, 256-q chunk g&1); lane: parity p=u>>4,
//            l-pair lp=u&15 (float2 loads along L, 8-deep batching).
//            Per-lane strict-> top-3 over 64 monotone q's -> sv/si.
//   Phase 1: 128 threads merge 8 partials per (h,l) with TIE-EXACT compare,
//            softmax, weights + premultiplied row offsets -> wt_s/rid_s.
//   Phase 2+3 (per 256-d half): wave g gathers rows for l's g*4..+3 (all 64
//            lanes on the SAME emb row, float4/lane, L2-resident) -> tile;
//            then transposed float4-over-l stores into out(B,d,L).
__global__ __launch_bounds__(512, 4) void fused_kernel(
    const float* __restrict__ logits,
    const float* __restrict__ emb0, const float* __restrict__ emb1,
    const float* __restrict__ emb2, const float* __restrict__ emb3,
    float* __restrict__ out) {
  const int t  = threadIdx.x;
  const int u  = t & 63;
  const int g  = t >> 6;        // wave 0..7
  const int lt = blockIdx.x;    // 0..63
  const int b  = blockIdx.y;    // 0..7
  const int l0 = lt * 32;

  __shared__ float          sv[4 * 8 * 32 * 3];   // 12288 B
  __shared__ unsigned short si[4 * 8 * 32 * 3];   //  6144 B
  __shared__ float          tile[32 * 260];       // 33280 B (pad 4: d-half+4)
  __shared__ float          wt_s[4][32][3];       //  1536 B
  __shared__ int            rid_s[4][32][3];      //  1536 B

  // ---------------- Phase 0: scan ----------------
  {
    const int h  = g >> 1;      // head
    const int s  = g & 1;       // 256-q chunk
    const int p  = u >> 4;      // q parity 0..3
    const int lp = u & 15;      // l-pair; l = l0 + lp*2 (+0/1)
    const float2* base = (const float2*)(
        logits + ((size_t)((b * 4 + h) * QQ + s * 256 + p) * LL) + l0 + lp * 2);

    float v0[2], v1[2], v2[2];
    int   i0[2], i1[2], i2[2];
#pragma unroll
    for (int j = 0; j < 2; ++j) {
      v0[j] = v1[j] = v2[j] = -INFINITY;
      i0[j] = i1[j] = i2[j] = 0;
    }

    float2 buf[8];
    for (int batch = 0; batch < 8; ++batch) {  // 8 loads in flight
#pragma unroll
      for (int j = 0; j < 8; ++j)
        buf[j] = base[(size_t)(batch * 8 + j) * (LL * 2)];  // q += 4 per step
#pragma unroll
      for (int j = 0; j < 8; ++j) {
        const int q = s * 256 + (batch * 8 + j) * 4 + p;  // increasing per lane
        top3_insert(buf[j].x, q, v0[0], v1[0], v2[0], i0[0], i1[0], i2[0]);
        top3_insert(buf[j].y, q, v0[1], v1[1], v2[1], i0[1], i1[1], i2[1]);
      }
    }

    const int sp = s * 4 + p;  // 0..7
#pragma unroll
    for (int j = 0; j < 2; ++j) {
      const int li = lp * 2 + j;
      const int bi = ((h * 8 + sp) * 32 + li) * 3;
      sv[bi + 0] = v0[j]; sv[bi + 1] = v1[j]; sv[bi + 2] = v2[j];
      si[bi + 0] = (unsigned short)i0[j];
      si[bi + 1] = (unsigned short)i1[j];
      si[bi + 2] = (unsigned short)i2[j];
    }
  }
  __syncthreads();

  // ---------------- Phase 1: tie-exact merge + softmax ----------------
  if (t < 128) {
    const int h  = t >> 5;
    const int li = t & 31;
    float m0 = -INFINITY, m1 = -INFINITY, m2 = -INFINITY;
    int   j0 = 0, j1 = 0, j2 = 0;
#pragma unroll
    for (int sp = 0; sp < 8; ++sp) {
      const int bi = ((h * 8 + sp) * 32 + li) * 3;
#pragma unroll
      for (int k = 0; k < 3; ++k)
        top3_tie(sv[bi + k], (int)si[bi + k], m0, m1, m2, j0, j1, j2);
    }
    float e1 = __expf(m1 - m0), e2 = __expf(m2 - m0);
    float inv = 1.0f / (1.0f + e1 + e2);
    wt_s[h][li][0] = inv;
    wt_s[h][li][1] = e1 * inv;
    wt_s[h][li][2] = e2 * inv;
    rid_s[h][li][0] = j0 * DD;  // premultiplied row offsets
    rid_s[h][li][1] = j1 * DD;
    rid_s[h][li][2] = j2 * DD;
  }
  __syncthreads();

  // ---------------- Phases 2+3: gather/combine + store, per 256-d half ----
  const float* embs[4] = {emb0, emb1, emb2, emb3};
  for (int dh = 0; dh < 2; ++dh) {
    // Phase 2: wave g -> l's g*4..g*4+3; all lanes on the same emb row.
#pragma unroll
    for (int j = 0; j < 4; ++j) {
      const int li = g * 4 + j;
      float wt[12];
      int   off[12];
#pragma unroll
      for (int h = 0; h < 4; ++h)
#pragma unroll
        for (int k = 0; k < 3; ++k) {
          wt[h * 3 + k]  = wt_s[h][li][k];   // LDS broadcast
          off[h * 3 + k] = rid_s[h][li][k];
        }
      const int d = dh * 256 + u * 4;
      float a0 = 0.f, a1 = 0.f, a2 = 0.f, a3 = 0.f;
#pragma unroll
      for (int h = 0; h < 4; ++h) {
        const float* eb = embs[h];
#pragma unroll
        for (int k = 0; k < 3; ++k) {
          const float4 e = *(const float4*)(eb + off[h * 3 + k] + d);
          const float wv = wt[h * 3 + k];
          a0 += wv * e.x; a1 += wv * e.y; a2 += wv * e.z; a3 += wv * e.w;
        }
      }
      *(float4*)&tile[li * 260 + u * 4] = make_float4(a0, a1, a2, a3);
    }
    __syncthreads();

    // Phase 3: transposed store. lg = l-group, dof = d offset in half.
    {
      const int lg  = t & 7;    // 0..7 -> l = l0 + lg*4 .. +3
      const int dof = t >> 3;   // 0..63
      float* outb = out + (size_t)b * DD * LL + l0 + lg * 4;
#pragma unroll
      for (int dd = 0; dd < 4; ++dd) {
        const int dl = dd * 64 + dof;  // 0..255 within half
        float4 r;
        r.x = tile[(lg * 4 + 0) * 260 + dl];
        r.y = tile[(lg * 4 + 1) * 260 + dl];
        r.z = tile[(lg * 4 + 2) * 260 + dl];
        r.w = tile[(lg * 4 + 3) * 260 + dl];
        *(float4*)(outb + (size_t)(dh * 256 + dl) * LL) = r;
      }
    }
    __syncthreads();  // tile reused by next d-half
  }
}

extern "C" void kernel_launch(void* const* d_in, const int* in_sizes, int n_in,
                              void* d_out, int out_size, void* d_ws,
                              size_t ws_size, hipStream_t stream) {
  const float* logits = (const float*)d_in[0];
  const float* emb0   = (const float*)d_in[1];
  const float* emb1   = (const float*)d_in[2];
  const float* emb2   = (const float*)d_in[3];
  const float* emb3   = (const float*)d_in[4];
  float*       out    = (float*)d_out;

  dim3 grid(LL / 32, BB);  // 512 blocks x 512 threads; 2 blocks/CU
  fused_kernel<<<grid, 512, 0, stream>>>(logits, emb0, emb1, emb2, emb3, out);
}